// Round 1
// baseline (298.705 us; speedup 1.0000x reference)
//
#include <hip/hip_runtime.h>
#include <hip/hip_bf16.h>
#include <hip/hip_cooperative_groups.h>

namespace cg = cooperative_groups;

#define Hh 96
#define Ww 128
#define Cc 21
#define Nn (Hh * Ww)       // 12288
#define COLSZ (Hh * Cc)    // 2016 elements per image column
#define NF4 (COLSZ / 4)    // 504 quads per column
#define RAD 10             // dropped mass ~2e-4 rel; ~<=0.01 abs in q: ok
#define TSTR 120           // tbuf per-channel stride (116 used, mult-of-4)
#define NT 512             // threads per block: 8 waves -> 2 waves/SIMD

// bf16 helpers: p is stored packed bf16 (2 per uint) to halve Phase-A bytes.
__device__ __forceinline__ unsigned short f2bf(float f) {
  unsigned int u = __float_as_uint(f);
  u += 0x7fffu + ((u >> 16) & 1u);   // round-to-nearest-even
  return (unsigned short)(u >> 16);
}
__device__ __forceinline__ float bf2f_lo(unsigned int u) {
  return __uint_as_float(u << 16);
}
__device__ __forceinline__ float bf2f_hi(unsigned int u) {
  return __uint_as_float(u & 0xffff0000u);
}

// ---------------------------------------------------------------------------
// Fully fused CRF: softmax0 + 5 iterations in ONE cooperative kernel.
// Rationale (R8): 6 dependent launches at ~15-20us each were dominated by
// dispatch round-trips + 5x redundant per-iteration setup (u gather, M=cm@W
// 21^3 matmul, w/ny tables, tbuf pad zeroing). Real work is ~32 MFLOP/iter
// (~0.2us at fp32 vector rate) -> launch-latency-bound. 128 blocks <= 256 CUs
// so cooperative co-residency is guaranteed; cross-column exchange of p
// happens through global bf16 buffers with grid.sync() between iterations.
// ---------------------------------------------------------------------------
__global__ __launch_bounds__(NT) void crf_fused_k(
    const float* __restrict__ u, const float* __restrict__ Ws,
    const float* __restrict__ Wb, const float* __restrict__ compat,
    unsigned int* __restrict__ pa, unsigned int* __restrict__ pb,
    float* __restrict__ qout) {
  cg::grid_group grid = cg::this_grid();
  const int x = blockIdx.x, tid = threadIdx.x;

  __shared__ float w_ld[RAD + 1];
  __shared__ float ny_ld[Hh];
  __shared__ float M_ld[Cc * Cc];
  __shared__ float wsum_ld[Cc * Cc];
  __shared__ float cm_ld[Cc * Cc];
  __shared__ __align__(16) float tbuf[Cc * TSTR];  // [c][10|96|10+pad]
  __shared__ __align__(16) float sbuf[COLSZ];      // [h][c]
  __shared__ __align__(16) float qbuf[COLSZ];      // [h][c]

  // ---- u gather (registers, kept across all 5 iterations) ----
  float uval[4];
  #pragma unroll
  for (int k = 0; k < 4; ++k) {
    int i = tid + NT * k;
    uval[k] = (i < COLSZ) ? u[((size_t)(i / Cc) * Ww + x) * Cc + (i % Cc)] : 0.f;
  }

  // ---- per-block precompute, ONCE for the whole pipeline ----
  if (tid <= RAD) w_ld[tid] = __expf((float)(tid * tid) * (-1.f / 18.f));
  if (tid < Cc * Cc) { wsum_ld[tid] = Ws[tid] + Wb[tid]; cm_ld[tid] = compat[tid]; }
  // zero vertical pads of tbuf (never overwritten afterwards)
  {
    int i = tid;                       // Cc*2*RAD = 420 < NT: single pass
    if (i < Cc * 2 * RAD) {
      int c = i / (2 * RAD), g = i % (2 * RAD);
      tbuf[c * TSTR + (g < RAD ? g : Hh + g)] = 0.f;
    }
  }
  __syncthreads();
  if (tid < Cc * Cc) {
    int a = tid / Cc, b = tid % Cc;
    float s = 0.f;
    #pragma unroll
    for (int kk = 0; kk < Cc; ++kk) s += cm_ld[a * Cc + kk] * wsum_ld[kk * Cc + b];
    M_ld[tid] = s;  // consumed in Phase C (covered by barriers below)
  }
  if (tid < Hh) {
    float s = 0.f;
    #pragma unroll
    for (int d = -RAD; d <= RAD; ++d) {
      int hp = tid + d;
      if (hp >= 0 && hp < Hh) s += w_ld[d < 0 ? -d : d];
    }
    ny_ld[tid] = s;  // truncated consistently with the blur
  }
  float nxv = 0.f;
  #pragma unroll
  for (int d = -RAD; d <= RAD; ++d) {
    int xp = x + d;
    if (xp >= 0 && xp < Ww) nxv += w_ld[d < 0 ? -d : d];
  }

  // ---- p0 = softmax(u): into qbuf, pack bf16 -> pa ----
  #pragma unroll
  for (int k = 0; k < 4; ++k) {
    int i = tid + NT * k;
    if (i < COLSZ) qbuf[i] = uval[k];
  }
  __syncthreads();
  if (tid < Hh) {
    float* p = qbuf + tid * Cc;
    float v[Cc];
    float m = -1e30f;
    #pragma unroll
    for (int c = 0; c < Cc; ++c) { v[c] = p[c]; m = fmaxf(m, v[c]); }
    float s = 0.f;
    #pragma unroll
    for (int c = 0; c < Cc; ++c) { v[c] = __expf(v[c] - m); s += v[c]; }
    float inv = 1.f / s;
    #pragma unroll
    for (int c = 0; c < Cc; ++c) p[c] = v[c] * inv;
  }
  __syncthreads();
  if (tid < NF4) {   // pack 4 fp32 -> 2 uints (4 bf16), 8B coalesced store
    float4 v = *(const float4*)(qbuf + 4 * tid);
    uint2 o;
    o.x = (unsigned int)f2bf(v.x) | ((unsigned int)f2bf(v.y) << 16);
    o.y = (unsigned int)f2bf(v.z) | ((unsigned int)f2bf(v.w) << 16);
    *(uint2*)(pa + (size_t)x * (COLSZ / 2) + 2 * tid) = o;
  }
  __threadfence();   // make p0 visible device-wide before the grid barrier
  grid.sync();

  const unsigned int* pin = pa;
  unsigned int* pout = pb;

  for (int it = 0; it < 5; ++it) {
    const int last = (it == 4);

    // ---- Phase A: H-blur from global bf16 p (1 uint2/thread, coalesced) ----
    float4 acc = {0.f, 0.f, 0.f, 0.f};
    const bool af = (tid < NF4);
    for (int xs = x - RAD; xs <= x + RAD; ++xs) {  // bounds block-uniform
      if (xs < 0 || xs >= Ww) continue;
      int ad = xs - x; if (ad < 0) ad = -ad;
      float wv = w_ld[ad];
      if (af) {
        uint2 v = *(const uint2*)(pin + (size_t)xs * (COLSZ / 2) + 2 * tid);
        acc.x += wv * bf2f_lo(v.x); acc.y += wv * bf2f_hi(v.x);
        acc.z += wv * bf2f_lo(v.y); acc.w += wv * bf2f_hi(v.y);
      }
    }
    if (af) {  // scatter into transposed padded tbuf [c][RAD+h]
      float a4[4] = {acc.x, acc.y, acc.z, acc.w};
      #pragma unroll
      for (int e = 0; e < 4; ++e) {
        int i = 4 * tid + e;
        tbuf[(i % Cc) * TSTR + RAD + (i / Cc)] = a4[e];
      }
    }
    __syncthreads();

    // ---- Phase B: V-blur (aligned float4 LDS reads) + normalize ----
    if (tid < NF4) {               // 504 = 21 c * 24 h-quads
      int c = tid / 24, q = tid % 24;
      int h0 = 4 * q;
      const float* base = tbuf + c * TSTR + h0;  // padded idx of h0-RAD
      float r[4] = {0.f, 0.f, 0.f, 0.f};
      #pragma unroll
      for (int jj = 0; jj < 6; ++jj) {      // offsets 0..23 cover d in [-10,13]
        float4 tv = *(const float4*)(base + 4 * jj);
        float tvv[4] = {tv.x, tv.y, tv.z, tv.w};
        #pragma unroll
        for (int kk = 0; kk < 4; ++kk) {
          #pragma unroll
          for (int o = 0; o < 4; ++o) {
            int d = 4 * jj + kk - RAD - o;  // compile-time after unroll
            int ad = d < 0 ? -d : d;
            if (ad <= RAD) r[o] += w_ld[ad] * tvv[kk];
          }
        }
      }
      #pragma unroll
      for (int o = 0; o < 4; ++o)
        sbuf[(h0 + o) * Cc + c] = r[o] / (nxv * ny_ld[h0 + o]);
    }
    __syncthreads();

    // ---- Phase C: q = u - M@s, then softmax->bf16 (or raw fp32 if last) ----
    #pragma unroll
    for (int k = 0; k < 4; ++k) {
      int i = tid + NT * k;
      if (i < COLSZ) {
        int h = i / Cc, c = i % Cc;
        float a = 0.f;
        #pragma unroll
        for (int b = 0; b < Cc; ++b) a += M_ld[c * Cc + b] * sbuf[h * Cc + b];
        qbuf[i] = uval[k] - a;
      }
    }
    __syncthreads();
    if (last) {                    // block/grid-uniform branch
      if (tid < NF4)
        *(float4*)(qout + (size_t)x * COLSZ + 4 * tid) = *(const float4*)(qbuf + 4 * tid);
    } else {
      if (tid < Hh) {
        float* p = qbuf + tid * Cc;
        float v[Cc];
        float m = -1e30f;
        #pragma unroll
        for (int c = 0; c < Cc; ++c) { v[c] = p[c]; m = fmaxf(m, v[c]); }
        float s = 0.f;
        #pragma unroll
        for (int c = 0; c < Cc; ++c) { v[c] = __expf(v[c] - m); s += v[c]; }
        float inv = 1.f / s;
        #pragma unroll
        for (int c = 0; c < Cc; ++c) p[c] = v[c] * inv;
      }
      __syncthreads();
      if (tid < NF4) {
        float4 v = *(const float4*)(qbuf + 4 * tid);
        uint2 o;
        o.x = (unsigned int)f2bf(v.x) | ((unsigned int)f2bf(v.y) << 16);
        o.y = (unsigned int)f2bf(v.z) | ((unsigned int)f2bf(v.w) << 16);
        *(uint2*)(pout + (size_t)x * (COLSZ / 2) + 2 * tid) = o;
      }
      __threadfence();   // p visible device-wide before the grid barrier
      grid.sync();
      const unsigned int* t = pin; pin = pout; pout = (unsigned int*)t;
    }
  }
}

// ---------------------------------------------------------------------------
extern "C" void kernel_launch(void* const* d_in, const int* in_sizes, int n_in,
                              void* d_out, int out_size, void* d_ws, size_t ws_size,
                              hipStream_t stream) {
  const float* u      = (const float*)d_in[0];  // (1,H,W,C)
  // d_in[1] = rgb: DEAD (replicated source bug uses spatial_out twice)
  const float* Ws     = (const float*)d_in[2];
  const float* Wb     = (const float*)d_in[3];
  const float* compat = (const float*)d_in[4];
  float* out = (float*)d_out;

  unsigned int* pa = (unsigned int*)d_ws;      // bf16-packed [W][H][C]/2 uints
  unsigned int* pb = pa + (size_t)Cc * Nn / 2;

  void* args[] = {(void*)&u, (void*)&Ws, (void*)&Wb, (void*)&compat,
                  (void*)&pa, (void*)&pb, (void*)&out};
  hipLaunchCooperativeKernel((const void*)crf_fused_k, dim3(Ww), dim3(NT),
                             args, 0, stream);
}

// Round 3
// 186.841 us; speedup vs baseline: 1.5987x; 1.5987x over previous
//
#include <hip/hip_runtime.h>
#include <hip/hip_bf16.h>

#define Hh 96
#define Ww 128
#define Cc 21
#define Nn (Hh * Ww)       // 12288
#define COLSZ (Hh * Cc)    // 2016 elements per image column
#define NF4 (COLSZ / 4)    // 504 quads per column
#define RAD 10             // dropped mass ~2e-4 rel; ~<=0.01 abs in q: ok
#define TSTR 120           // tbuf per-channel stride (116 used, mult-of-4)
#define NT 512             // threads per block: 8 waves -> 2 waves/SIMD
#define NBAR 5             // grid barriers per launch (1 after p0 + 4 in loop)

// bf16 helpers: p is stored packed bf16 (2 per uint) to halve Phase-A bytes.
__device__ __forceinline__ unsigned short f2bf(float f) {
  unsigned int u = __float_as_uint(f);
  u += 0x7fffu + ((u >> 16) & 1u);   // round-to-nearest-even
  return (unsigned short)(u >> 16);
}
__device__ __forceinline__ float bf2f_lo(unsigned int u) {
  return __uint_as_float(u << 16);
}
__device__ __forceinline__ float bf2f_hi(unsigned int u) {
  return __uint_as_float(u & 0xffff0000u);
}

// ---------------------------------------------------------------------------
// Grid barrier, R10 (un-hangable by construction).
// R8: cg::grid.sync() ~35us each (all-wave spin). R9: custom sense-reversing
// barrier with persistent device-global state -> container died (presumed
// hang; unbounded spin + subtle reset race). R10 changes:
//   * one MONOTONIC counter per barrier epoch (64B-spaced, in d_ws): written
//     once per block, never reset, no sense flag -> no reuse race exists.
//   * state zeroed EVERY launch by hipMemsetAsync before the dispatch
//     (graph-capturable) -> zero cross-launch state.
//   * spin is BOUNDED: on logic error we produce a wrong answer (test fails
//     with numbers), never a dead container.
// Only tid0 per block arrives/spins (127 spinners, not 1024 waves).
// Release: __threadfence (vmcnt drain + L2 writeback) publishes this XCD's
// p-lines to IF before arriving. Acquire: __threadfence after the spin
// invalidates stale local-L2 lines before Phase-A loads.
// ---------------------------------------------------------------------------
__device__ __forceinline__ void gridbar(unsigned* bar, int e) {
  __syncthreads();                 // all stores of this block issued
  if (threadIdx.x == 0) {
    unsigned* c = bar + e * 16;    // 64B per-epoch cache line
    __threadfence();               // publish p to IF (wbL2)
    __hip_atomic_fetch_add(c, 1u, __ATOMIC_ACQ_REL, __HIP_MEMORY_SCOPE_AGENT);
    for (int spin = 0; spin < (1 << 22); ++spin) {   // bounded watchdog
      if (__hip_atomic_load(c, __ATOMIC_RELAXED, __HIP_MEMORY_SCOPE_AGENT)
          >= (unsigned)Ww) break;
      __builtin_amdgcn_s_sleep(2);
    }
    __threadfence();               // drop stale L2 lines (invalidate)
  }
  __syncthreads();
}

// ---------------------------------------------------------------------------
// Fully fused CRF: softmax0 + 5 iterations in ONE cooperative kernel.
// 128 blocks <= 256 CUs so co-residency is guaranteed; cross-column exchange
// of p goes through global bf16 buffers with gridbar() between iterations.
// Per-iteration setup (u gather, M=cm@W, w/ny tables, pad zeroing) hoisted.
// ---------------------------------------------------------------------------
__global__ __launch_bounds__(NT) void crf_fused_k(
    const float* __restrict__ u, const float* __restrict__ Ws,
    const float* __restrict__ Wb, const float* __restrict__ compat,
    unsigned int* __restrict__ pa, unsigned int* __restrict__ pb,
    unsigned int* __restrict__ bar, float* __restrict__ qout) {
  const int x = blockIdx.x, tid = threadIdx.x;

  __shared__ float w_ld[RAD + 1];
  __shared__ float ny_ld[Hh];
  __shared__ float M_ld[Cc * Cc];
  __shared__ float wsum_ld[Cc * Cc];
  __shared__ float cm_ld[Cc * Cc];
  __shared__ __align__(16) float tbuf[Cc * TSTR];  // [c][10|96|10+pad]
  __shared__ __align__(16) float sbuf[COLSZ];      // [h][c]
  __shared__ __align__(16) float qbuf[COLSZ];      // [h][c]

  // ---- u gather (registers, kept across all 5 iterations) ----
  float uval[4];
  #pragma unroll
  for (int k = 0; k < 4; ++k) {
    int i = tid + NT * k;
    uval[k] = (i < COLSZ) ? u[((size_t)(i / Cc) * Ww + x) * Cc + (i % Cc)] : 0.f;
  }

  // ---- per-block precompute, ONCE for the whole pipeline ----
  if (tid <= RAD) w_ld[tid] = __expf((float)(tid * tid) * (-1.f / 18.f));
  if (tid < Cc * Cc) { wsum_ld[tid] = Ws[tid] + Wb[tid]; cm_ld[tid] = compat[tid]; }
  // zero vertical pads of tbuf (never overwritten afterwards)
  {
    int i = tid;                       // Cc*2*RAD = 420 < NT: single pass
    if (i < Cc * 2 * RAD) {
      int c = i / (2 * RAD), g = i % (2 * RAD);
      tbuf[c * TSTR + (g < RAD ? g : Hh + g)] = 0.f;
    }
  }
  __syncthreads();
  if (tid < Cc * Cc) {
    int a = tid / Cc, b = tid % Cc;
    float s = 0.f;
    #pragma unroll
    for (int kk = 0; kk < Cc; ++kk) s += cm_ld[a * Cc + kk] * wsum_ld[kk * Cc + b];
    M_ld[tid] = s;  // consumed in Phase C (covered by barriers below)
  }
  if (tid < Hh) {
    float s = 0.f;
    #pragma unroll
    for (int d = -RAD; d <= RAD; ++d) {
      int hp = tid + d;
      if (hp >= 0 && hp < Hh) s += w_ld[d < 0 ? -d : d];
    }
    ny_ld[tid] = s;  // truncated consistently with the blur
  }
  float nxv = 0.f;
  #pragma unroll
  for (int d = -RAD; d <= RAD; ++d) {
    int xp = x + d;
    if (xp >= 0 && xp < Ww) nxv += w_ld[d < 0 ? -d : d];
  }

  // ---- p0 = softmax(u): into qbuf, pack bf16 -> pa ----
  #pragma unroll
  for (int k = 0; k < 4; ++k) {
    int i = tid + NT * k;
    if (i < COLSZ) qbuf[i] = uval[k];
  }
  __syncthreads();
  if (tid < Hh) {
    float* p = qbuf + tid * Cc;
    float v[Cc];
    float m = -1e30f;
    #pragma unroll
    for (int c = 0; c < Cc; ++c) { v[c] = p[c]; m = fmaxf(m, v[c]); }
    float s = 0.f;
    #pragma unroll
    for (int c = 0; c < Cc; ++c) { v[c] = __expf(v[c] - m); s += v[c]; }
    float inv = 1.f / s;
    #pragma unroll
    for (int c = 0; c < Cc; ++c) p[c] = v[c] * inv;
  }
  __syncthreads();
  if (tid < NF4) {   // pack 4 fp32 -> 2 uints (4 bf16), 8B coalesced store
    float4 v = *(const float4*)(qbuf + 4 * tid);
    uint2 o;
    o.x = (unsigned int)f2bf(v.x) | ((unsigned int)f2bf(v.y) << 16);
    o.y = (unsigned int)f2bf(v.z) | ((unsigned int)f2bf(v.w) << 16);
    *(uint2*)(pa + (size_t)x * (COLSZ / 2) + 2 * tid) = o;
  }
  gridbar(bar, 0);   // p0 visible device-wide

  const unsigned int* pin = pa;
  unsigned int* pout = pb;

  for (int it = 0; it < 5; ++it) {
    const int last = (it == 4);

    // ---- Phase A: H-blur from global bf16 p (1 uint2/thread, coalesced) ----
    float4 acc = {0.f, 0.f, 0.f, 0.f};
    const bool af = (tid < NF4);
    for (int xs = x - RAD; xs <= x + RAD; ++xs) {  // bounds block-uniform
      if (xs < 0 || xs >= Ww) continue;
      int ad = xs - x; if (ad < 0) ad = -ad;
      float wv = w_ld[ad];
      if (af) {
        uint2 v = *(const uint2*)(pin + (size_t)xs * (COLSZ / 2) + 2 * tid);
        acc.x += wv * bf2f_lo(v.x); acc.y += wv * bf2f_hi(v.x);
        acc.z += wv * bf2f_lo(v.y); acc.w += wv * bf2f_hi(v.y);
      }
    }
    if (af) {  // scatter into transposed padded tbuf [c][RAD+h]
      float a4[4] = {acc.x, acc.y, acc.z, acc.w};
      #pragma unroll
      for (int e = 0; e < 4; ++e) {
        int i = 4 * tid + e;
        tbuf[(i % Cc) * TSTR + RAD + (i / Cc)] = a4[e];
      }
    }
    __syncthreads();

    // ---- Phase B: V-blur (aligned float4 LDS reads) + normalize ----
    if (tid < NF4) {               // 504 = 21 c * 24 h-quads
      int c = tid / 24, q = tid % 24;
      int h0 = 4 * q;
      const float* base = tbuf + c * TSTR + h0;  // padded idx of h0-RAD
      float r[4] = {0.f, 0.f, 0.f, 0.f};
      #pragma unroll
      for (int jj = 0; jj < 6; ++jj) {      // offsets 0..23 cover d in [-10,13]
        float4 tv = *(const float4*)(base + 4 * jj);
        float tvv[4] = {tv.x, tv.y, tv.z, tv.w};
        #pragma unroll
        for (int kk = 0; kk < 4; ++kk) {
          #pragma unroll
          for (int o = 0; o < 4; ++o) {
            int d = 4 * jj + kk - RAD - o;  // compile-time after unroll
            int ad = d < 0 ? -d : d;
            if (ad <= RAD) r[o] += w_ld[ad] * tvv[kk];
          }
        }
      }
      #pragma unroll
      for (int o = 0; o < 4; ++o)
        sbuf[(h0 + o) * Cc + c] = r[o] / (nxv * ny_ld[h0 + o]);
    }
    __syncthreads();

    // ---- Phase C: q = u - M@s, then softmax->bf16 (or raw fp32 if last) ----
    #pragma unroll
    for (int k = 0; k < 4; ++k) {
      int i = tid + NT * k;
      if (i < COLSZ) {
        int h = i / Cc, c = i % Cc;
        float a = 0.f;
        #pragma unroll
        for (int b = 0; b < Cc; ++b) a += M_ld[c * Cc + b] * sbuf[h * Cc + b];
        qbuf[i] = uval[k] - a;
      }
    }
    __syncthreads();
    if (last) {                    // block/grid-uniform branch
      if (tid < NF4)
        *(float4*)(qout + (size_t)x * COLSZ + 4 * tid) = *(const float4*)(qbuf + 4 * tid);
    } else {
      if (tid < Hh) {
        float* p = qbuf + tid * Cc;
        float v[Cc];
        float m = -1e30f;
        #pragma unroll
        for (int c = 0; c < Cc; ++c) { v[c] = p[c]; m = fmaxf(m, v[c]); }
        float s = 0.f;
        #pragma unroll
        for (int c = 0; c < Cc; ++c) { v[c] = __expf(v[c] - m); s += v[c]; }
        float inv = 1.f / s;
        #pragma unroll
        for (int c = 0; c < Cc; ++c) p[c] = v[c] * inv;
      }
      __syncthreads();
      if (tid < NF4) {
        float4 v = *(const float4*)(qbuf + 4 * tid);
        uint2 o;
        o.x = (unsigned int)f2bf(v.x) | ((unsigned int)f2bf(v.y) << 16);
        o.y = (unsigned int)f2bf(v.z) | ((unsigned int)f2bf(v.w) << 16);
        *(uint2*)(pout + (size_t)x * (COLSZ / 2) + 2 * tid) = o;
      }
      gridbar(bar, 1 + it);        // p visible device-wide
      const unsigned int* t = pin; pin = pout; pout = (unsigned int*)t;
    }
  }
}

// ---------------------------------------------------------------------------
extern "C" void kernel_launch(void* const* d_in, const int* in_sizes, int n_in,
                              void* d_out, int out_size, void* d_ws, size_t ws_size,
                              hipStream_t stream) {
  const float* u      = (const float*)d_in[0];  // (1,H,W,C)
  // d_in[1] = rgb: DEAD (replicated source bug uses spatial_out twice)
  const float* Ws     = (const float*)d_in[2];
  const float* Wb     = (const float*)d_in[3];
  const float* compat = (const float*)d_in[4];
  float* out = (float*)d_out;

  unsigned int* pa  = (unsigned int*)d_ws;     // bf16-packed [W][H][C]/2 uints
  unsigned int* pb  = pa + (size_t)Cc * Nn / 2;
  unsigned int* bar = pb + (size_t)Cc * Nn / 2;  // NBAR x 64B epoch counters

  // Zero barrier state EVERY launch (graph-capturable stream op): each
  // launch/replay starts from a pristine monotonic-counter state.
  hipMemsetAsync(bar, 0, NBAR * 16 * sizeof(unsigned), stream);

  void* args[] = {(void*)&u, (void*)&Ws, (void*)&Wb, (void*)&compat,
                  (void*)&pa, (void*)&pb, (void*)&bar, (void*)&out};
  hipLaunchCooperativeKernel((const void*)crf_fused_k, dim3(Ww), dim3(NT),
                             args, 0, stream);
}

// Round 4
// 119.638 us; speedup vs baseline: 2.4967x; 1.5617x over previous
//
#include <hip/hip_runtime.h>
#include <hip/hip_bf16.h>

#define Hh 96
#define Ww 128
#define Cc 21
#define Nn (Hh * Ww)       // 12288
#define COLSZ (Hh * Cc)    // 2016 elements per image column
#define NF4 (COLSZ / 4)    // 504 quads per column
#define RAD 10             // dropped mass ~2e-4 rel; ~<=0.01 abs in q: ok
#define TSTR 120           // tbuf per-channel stride (116 used, mult-of-4)
#define NT 512             // threads per block: 8 waves -> 2 waves/SIMD
#define NBAR 5             // grid barriers per launch (1 after p0 + 4 in loop)

// bf16 helpers: p is stored packed bf16 (2 per uint) to halve Phase-A bytes.
__device__ __forceinline__ unsigned short f2bf(float f) {
  unsigned int u = __float_as_uint(f);
  u += 0x7fffu + ((u >> 16) & 1u);   // round-to-nearest-even
  return (unsigned short)(u >> 16);
}
__device__ __forceinline__ float bf2f_lo(unsigned int u) {
  return __uint_as_float(u << 16);
}
__device__ __forceinline__ float bf2f_hi(unsigned int u) {
  return __uint_as_float(u & 0xffff0000u);
}

// ---------------------------------------------------------------------------
// R11. Two changes vs R10 (104us kernel + ~83us cooperative-launch overhead):
// 1) NORMAL launch (no hipLaunchCooperativeKernel): we use no cg primitives;
//    128 blocks x (8 waves, 32KB LDS) co-reside trivially on 256 CUs, and the
//    bounded spin turns any scheduling pathology into a wrong answer, not a
//    hang. Normal launches ride the harness's graph replay (the R8/R10 e2e
//    minus kernel gap of ~75-83us was the cooperative-launch path).
// 2) FENCELESS barrier: R10 spent ~16us/barrier in __threadfence pairs
//    (buffer_wbl2 + buffer_inv L2-wide maintenance, serializing across the
//    16 blocks/XCD). Those fences exist only to make CACHED p-stores
//    coherent. Instead, ALL p accesses are agent-scope relaxed atomics
//    (8B __hip_atomic_load/store -> global_load/store_dwordx2 sc1): they
//    bypass the per-XCD L2 and are IF-coherent by construction. The barrier
//    is then just: __syncthreads (per-wave s_waitcnt vmcnt(0) before
//    s_barrier drains the sc1 stores to the coherent point) -> relaxed
//    agent fetch_add -> relaxed poll -> __syncthreads. Zero cache ops.
// Barrier state: one monotonic counter per epoch (64B apart) in d_ws,
// zeroed each launch by hipMemsetAsync (graph-capturable); spin bounded.
// ---------------------------------------------------------------------------
__device__ __forceinline__ void gridbar(unsigned* bar, int e) {
  __syncthreads();                 // drains vmcnt: block's sc1 stores complete
  if (threadIdx.x == 0) {
    unsigned* c = bar + e * 16;    // 64B per-epoch cache line
    __hip_atomic_fetch_add(c, 1u, __ATOMIC_RELAXED, __HIP_MEMORY_SCOPE_AGENT);
    for (int spin = 0; spin < (1 << 22); ++spin) {   // bounded watchdog
      if (__hip_atomic_load(c, __ATOMIC_RELAXED, __HIP_MEMORY_SCOPE_AGENT)
          >= (unsigned)Ww) break;
      __builtin_amdgcn_s_sleep(1);
    }
  }
  __syncthreads();
}

// ---------------------------------------------------------------------------
// Fully fused CRF: softmax0 + 5 iterations in ONE kernel, grid barriers
// between iterations; cross-column p exchange via IF-coherent sc1 accesses.
// Per-iteration setup (u gather, M=cm@W, w/ny tables, pad zeroing) hoisted.
// ---------------------------------------------------------------------------
__global__ __launch_bounds__(NT) void crf_fused_k(
    const float* __restrict__ u, const float* __restrict__ Ws,
    const float* __restrict__ Wb, const float* __restrict__ compat,
    unsigned long long* __restrict__ pa, unsigned long long* __restrict__ pb,
    unsigned int* __restrict__ bar, float* __restrict__ qout) {
  const int x = blockIdx.x, tid = threadIdx.x;

  __shared__ float w_ld[RAD + 1];
  __shared__ float ny_ld[Hh];
  __shared__ float M_ld[Cc * Cc];
  __shared__ float wsum_ld[Cc * Cc];
  __shared__ float cm_ld[Cc * Cc];
  __shared__ __align__(16) float tbuf[Cc * TSTR];  // [c][10|96|10+pad]
  __shared__ __align__(16) float sbuf[COLSZ];      // [h][c]
  __shared__ __align__(16) float qbuf[COLSZ];      // [h][c]

  // ---- u gather (registers, kept across all 5 iterations) ----
  float uval[4];
  #pragma unroll
  for (int k = 0; k < 4; ++k) {
    int i = tid + NT * k;
    uval[k] = (i < COLSZ) ? u[((size_t)(i / Cc) * Ww + x) * Cc + (i % Cc)] : 0.f;
  }

  // ---- per-block precompute, ONCE for the whole pipeline ----
  if (tid <= RAD) w_ld[tid] = __expf((float)(tid * tid) * (-1.f / 18.f));
  if (tid < Cc * Cc) { wsum_ld[tid] = Ws[tid] + Wb[tid]; cm_ld[tid] = compat[tid]; }
  // zero vertical pads of tbuf (never overwritten afterwards)
  {
    int i = tid;                       // Cc*2*RAD = 420 < NT: single pass
    if (i < Cc * 2 * RAD) {
      int c = i / (2 * RAD), g = i % (2 * RAD);
      tbuf[c * TSTR + (g < RAD ? g : Hh + g)] = 0.f;
    }
  }
  __syncthreads();
  if (tid < Cc * Cc) {
    int a = tid / Cc, b = tid % Cc;
    float s = 0.f;
    #pragma unroll
    for (int kk = 0; kk < Cc; ++kk) s += cm_ld[a * Cc + kk] * wsum_ld[kk * Cc + b];
    M_ld[tid] = s;  // consumed in Phase C (covered by barriers below)
  }
  if (tid < Hh) {
    float s = 0.f;
    #pragma unroll
    for (int d = -RAD; d <= RAD; ++d) {
      int hp = tid + d;
      if (hp >= 0 && hp < Hh) s += w_ld[d < 0 ? -d : d];
    }
    ny_ld[tid] = s;  // truncated consistently with the blur
  }
  float nxv = 0.f;
  #pragma unroll
  for (int d = -RAD; d <= RAD; ++d) {
    int xp = x + d;
    if (xp >= 0 && xp < Ww) nxv += w_ld[d < 0 ? -d : d];
  }

  // ---- p0 = softmax(u): into qbuf, pack bf16 -> pa (sc1 store) ----
  #pragma unroll
  for (int k = 0; k < 4; ++k) {
    int i = tid + NT * k;
    if (i < COLSZ) qbuf[i] = uval[k];
  }
  __syncthreads();
  if (tid < Hh) {
    float* p = qbuf + tid * Cc;
    float v[Cc];
    float m = -1e30f;
    #pragma unroll
    for (int c = 0; c < Cc; ++c) { v[c] = p[c]; m = fmaxf(m, v[c]); }
    float s = 0.f;
    #pragma unroll
    for (int c = 0; c < Cc; ++c) { v[c] = __expf(v[c] - m); s += v[c]; }
    float inv = 1.f / s;
    #pragma unroll
    for (int c = 0; c < Cc; ++c) p[c] = v[c] * inv;
  }
  __syncthreads();
  if (tid < NF4) {   // pack 4 fp32 -> 4 bf16 in one 8B coherent store
    float4 v = *(const float4*)(qbuf + 4 * tid);
    unsigned lo = (unsigned)f2bf(v.x) | ((unsigned)f2bf(v.y) << 16);
    unsigned hi = (unsigned)f2bf(v.z) | ((unsigned)f2bf(v.w) << 16);
    unsigned long long o = (unsigned long long)lo | ((unsigned long long)hi << 32);
    __hip_atomic_store(pa + (size_t)x * NF4 + tid, o,
                       __ATOMIC_RELAXED, __HIP_MEMORY_SCOPE_AGENT);
  }
  gridbar(bar, 0);   // p0 visible device-wide

  const unsigned long long* pin = pa;
  unsigned long long* pout = pb;

  for (int it = 0; it < 5; ++it) {
    const int last = (it == 4);

    // ---- Phase A: H-blur from IF-coherent bf16 p (8B sc1 load/tap) ----
    // Static 21-tap unroll: clamped column + zero weight at edges keeps the
    // loads unconditional & fully unrolled (registers, not scratch).
    float4 acc = {0.f, 0.f, 0.f, 0.f};
    const bool af = (tid < NF4);
    #pragma unroll
    for (int d = -RAD; d <= RAD; ++d) {
      int xs = x + d;
      int xc = xs < 0 ? 0 : (xs >= Ww ? Ww - 1 : xs);
      float wv = (xs == xc) ? w_ld[d < 0 ? -d : d] : 0.f;  // 0 for clamped
      if (af) {
        unsigned long long vv = __hip_atomic_load(
            pin + (size_t)xc * NF4 + tid,
            __ATOMIC_RELAXED, __HIP_MEMORY_SCOPE_AGENT);
        unsigned lo = (unsigned)vv, hi = (unsigned)(vv >> 32);
        acc.x += wv * bf2f_lo(lo); acc.y += wv * bf2f_hi(lo);
        acc.z += wv * bf2f_lo(hi); acc.w += wv * bf2f_hi(hi);
      }
    }
    if (af) {  // scatter into transposed padded tbuf [c][RAD+h]
      float a4[4] = {acc.x, acc.y, acc.z, acc.w};
      #pragma unroll
      for (int e = 0; e < 4; ++e) {
        int i = 4 * tid + e;
        tbuf[(i % Cc) * TSTR + RAD + (i / Cc)] = a4[e];
      }
    }
    __syncthreads();

    // ---- Phase B: V-blur (aligned float4 LDS reads) + normalize ----
    if (tid < NF4) {               // 504 = 21 c * 24 h-quads
      int c = tid / 24, q = tid % 24;
      int h0 = 4 * q;
      const float* base = tbuf + c * TSTR + h0;  // padded idx of h0-RAD
      float r[4] = {0.f, 0.f, 0.f, 0.f};
      #pragma unroll
      for (int jj = 0; jj < 6; ++jj) {      // offsets 0..23 cover d in [-10,13]
        float4 tv = *(const float4*)(base + 4 * jj);
        float tvv[4] = {tv.x, tv.y, tv.z, tv.w};
        #pragma unroll
        for (int kk = 0; kk < 4; ++kk) {
          #pragma unroll
          for (int o = 0; o < 4; ++o) {
            int d = 4 * jj + kk - RAD - o;  // compile-time after unroll
            int ad = d < 0 ? -d : d;
            if (ad <= RAD) r[o] += w_ld[ad] * tvv[kk];
          }
        }
      }
      #pragma unroll
      for (int o = 0; o < 4; ++o)
        sbuf[(h0 + o) * Cc + c] = r[o] / (nxv * ny_ld[h0 + o]);
    }
    __syncthreads();

    // ---- Phase C: q = u - M@s, then softmax->bf16 (or raw fp32 if last) ----
    #pragma unroll
    for (int k = 0; k < 4; ++k) {
      int i = tid + NT * k;
      if (i < COLSZ) {
        int h = i / Cc, c = i % Cc;
        float a = 0.f;
        #pragma unroll
        for (int b = 0; b < Cc; ++b) a += M_ld[c * Cc + b] * sbuf[h * Cc + b];
        qbuf[i] = uval[k] - a;
      }
    }
    __syncthreads();
    if (last) {                    // block-uniform branch
      if (tid < NF4)
        *(float4*)(qout + (size_t)x * COLSZ + 4 * tid) = *(const float4*)(qbuf + 4 * tid);
    } else {
      if (tid < Hh) {
        float* p = qbuf + tid * Cc;
        float v[Cc];
        float m = -1e30f;
        #pragma unroll
        for (int c = 0; c < Cc; ++c) { v[c] = p[c]; m = fmaxf(m, v[c]); }
        float s = 0.f;
        #pragma unroll
        for (int c = 0; c < Cc; ++c) { v[c] = __expf(v[c] - m); s += v[c]; }
        float inv = 1.f / s;
        #pragma unroll
        for (int c = 0; c < Cc; ++c) p[c] = v[c] * inv;
      }
      __syncthreads();
      if (tid < NF4) {
        float4 v = *(const float4*)(qbuf + 4 * tid);
        unsigned lo = (unsigned)f2bf(v.x) | ((unsigned)f2bf(v.y) << 16);
        unsigned hi = (unsigned)f2bf(v.z) | ((unsigned)f2bf(v.w) << 16);
        unsigned long long o = (unsigned long long)lo | ((unsigned long long)hi << 32);
        __hip_atomic_store(pout + (size_t)x * NF4 + tid, o,
                           __ATOMIC_RELAXED, __HIP_MEMORY_SCOPE_AGENT);
      }
      gridbar(bar, 1 + it);        // p visible device-wide
      const unsigned long long* t = pin; pin = pout;
      pout = (unsigned long long*)t;
    }
  }
}

// ---------------------------------------------------------------------------
extern "C" void kernel_launch(void* const* d_in, const int* in_sizes, int n_in,
                              void* d_out, int out_size, void* d_ws, size_t ws_size,
                              hipStream_t stream) {
  const float* u      = (const float*)d_in[0];  // (1,H,W,C)
  // d_in[1] = rgb: DEAD (replicated source bug uses spatial_out twice)
  const float* Ws     = (const float*)d_in[2];
  const float* Wb     = (const float*)d_in[3];
  const float* compat = (const float*)d_in[4];
  float* out = (float*)d_out;

  unsigned long long* pa = (unsigned long long*)d_ws;  // bf16x4 per 8B
  unsigned long long* pb = pa + (size_t)Ww * NF4;
  unsigned int* bar = (unsigned int*)(pb + (size_t)Ww * NF4);

  // Zero barrier state EVERY launch (graph-capturable stream op).
  hipMemsetAsync(bar, 0, NBAR * 16 * sizeof(unsigned), stream);

  crf_fused_k<<<dim3(Ww), dim3(NT), 0, stream>>>(u, Ws, Wb, compat,
                                                 pa, pb, bar, out);
}

// Round 5
// 89.569 us; speedup vs baseline: 3.3349x; 1.3357x over previous
//
#include <hip/hip_runtime.h>
#include <hip/hip_bf16.h>

#define Hh 96
#define Ww 128
#define Cc 21
#define Nn (Hh * Ww)       // 12288
#define COLSZ (Hh * Cc)    // 2016 elements per image column
#define NF4 (COLSZ / 4)    // 504 quads per column
#define RAD 10             // dropped mass ~2e-4 rel; ~<=0.01 abs in q: ok
#define TSTR 120           // tbuf per-channel stride (116 used, mult-of-4)
#define NT 512             // threads per block: 8 waves -> 2 waves/SIMD
#define FSTR 16            // flag stride in uints (64B line per column)

// bf16 helpers: p is stored packed bf16 (2 per uint) to halve Phase-A bytes.
__device__ __forceinline__ unsigned short f2bf(float f) {
  unsigned int u = __float_as_uint(f);
  u += 0x7fffu + ((u >> 16) & 1u);   // round-to-nearest-even
  return (unsigned short)(u >> 16);
}
__device__ __forceinline__ float bf2f_lo(unsigned int u) {
  return __uint_as_float(u << 16);
}
__device__ __forceinline__ float bf2f_hi(unsigned int u) {
  return __uint_as_float(u & 0xffff0000u);
}

// ---------------------------------------------------------------------------
// R12: per-column epoch flags replace the global barrier.
// R11 post-mortem: kernel 61us but VALUBusy 7.7% -> ~45us of waiting. The
// centralized barrier serialized 128 RMWs on ONE IF line (~2-5us/epoch) and
// imposed a global straggler (all columns wait for the slowest), 5 times.
// Column x only READS columns [x-10,x+10], so sync is local:
//   * after storing p for epoch e, tid0 posts flag[x] = e (relaxed sc1;
//     __syncthreads' per-wave vmcnt(0)-drain before s_barrier makes this a
//     release: all of the block's sc1 p-stores are IF-visible first).
//   * before Phase A of epoch e, lanes 0..20 each poll one clamped neighbor
//     flag (one parallel 8B sc1 load per round), then __syncthreads.
// No RMW contention (one writer per flag), no global straggler: columns
// pipeline in a wavefront.
// 2-BUFFER SAFETY: pa is written at epochs {1,3,5?no->1,3}, read at {2,4}...
// generally: a block writes buffer B at epoch e+1 only after its poll saw
// flag[c'] >= e+1 for ALL c' in x+-10. The readers of THIS column's slot in
// B at epoch e are exactly the blocks x' with |x'-x| <= 10 (symmetric
// radius), and flag[x'] >= e+1 is posted only after x' completed epoch e
// (its Phase-A reads of B included). So every read of the old value
// happens-before the overwrite. No third buffer needed.
// Spin is bounded: logic error => wrong answer, never a hung container.
// Flags zeroed every launch by hipMemsetAsync (graph-capturable).
// ---------------------------------------------------------------------------
__device__ __forceinline__ void wait_neighbors(const unsigned* __restrict__ flags,
                                               int x, unsigned needed) {
  if (threadIdx.x < 2 * RAD + 1) {
    int xc = x - RAD + (int)threadIdx.x;
    xc = xc < 0 ? 0 : (xc >= Ww ? Ww - 1 : xc);
    const unsigned* f = flags + (size_t)xc * FSTR;
    for (int spin = 0; spin < (1 << 20); ++spin) {   // bounded watchdog
      if (__hip_atomic_load(f, __ATOMIC_RELAXED, __HIP_MEMORY_SCOPE_AGENT)
          >= needed) break;
      __builtin_amdgcn_s_sleep(1);
    }
  }
  __syncthreads();
}

__device__ __forceinline__ void post_flag(unsigned* __restrict__ flags,
                                          int x, unsigned e) {
  __syncthreads();   // every wave drained vmcnt(0): all sc1 p-stores visible
  if (threadIdx.x == 0)
    __hip_atomic_store(flags + (size_t)x * FSTR, e,
                       __ATOMIC_RELAXED, __HIP_MEMORY_SCOPE_AGENT);
}

// Softmax over classes for each of the 96 rows of qbuf, 4 lanes per row
// (R12: was 96 serial threads; now 384 threads, shfl_xor group reduce).
__device__ __forceinline__ void softmax_rows(float* __restrict__ qbuf) {
  const int r = threadIdx.x >> 2, g = threadIdx.x & 3;
  if (r < Hh) {
    float v[6];
    float m = -1e30f;
    #pragma unroll
    for (int j = 0; j < 6; ++j) {
      int c = g + 4 * j;
      if (c < Cc) { v[j] = qbuf[r * Cc + c]; m = fmaxf(m, v[j]); }
    }
    m = fmaxf(m, __shfl_xor(m, 1));
    m = fmaxf(m, __shfl_xor(m, 2));
    float s = 0.f;
    #pragma unroll
    for (int j = 0; j < 6; ++j) {
      int c = g + 4 * j;
      if (c < Cc) { v[j] = __expf(v[j] - m); s += v[j]; }
    }
    s += __shfl_xor(s, 1);
    s += __shfl_xor(s, 2);
    float inv = 1.f / s;
    #pragma unroll
    for (int j = 0; j < 6; ++j) {
      int c = g + 4 * j;
      if (c < Cc) qbuf[r * Cc + c] = v[j] * inv;
    }
  }
}

// ---------------------------------------------------------------------------
// Fully fused CRF: softmax0 + 5 iterations, ONE normal launch, neighbor-flag
// sync; cross-column p exchange via IF-coherent (sc1) 8B accesses.
// ---------------------------------------------------------------------------
__global__ __launch_bounds__(NT) void crf_fused_k(
    const float* __restrict__ u, const float* __restrict__ Ws,
    const float* __restrict__ Wb, const float* __restrict__ compat,
    unsigned long long* __restrict__ pa, unsigned long long* __restrict__ pb,
    unsigned int* __restrict__ flags, float* __restrict__ qout) {
  const int x = blockIdx.x, tid = threadIdx.x;

  __shared__ float w_ld[RAD + 1];
  __shared__ float ny_ld[Hh];
  __shared__ float M_ld[Cc * Cc];
  __shared__ float wsum_ld[Cc * Cc];
  __shared__ float cm_ld[Cc * Cc];
  __shared__ __align__(16) float tbuf[Cc * TSTR];  // [c][10|96|10+pad]
  __shared__ __align__(16) float sbuf[COLSZ];      // [h][c]
  __shared__ __align__(16) float qbuf[COLSZ];      // [h][c]

  // ---- u gather (registers, kept across all 5 iterations) ----
  float uval[4];
  #pragma unroll
  for (int k = 0; k < 4; ++k) {
    int i = tid + NT * k;
    uval[k] = (i < COLSZ) ? u[((size_t)(i / Cc) * Ww + x) * Cc + (i % Cc)] : 0.f;
  }

  // ---- per-block precompute, ONCE for the whole pipeline ----
  if (tid <= RAD) w_ld[tid] = __expf((float)(tid * tid) * (-1.f / 18.f));
  if (tid < Cc * Cc) { wsum_ld[tid] = Ws[tid] + Wb[tid]; cm_ld[tid] = compat[tid]; }
  // zero vertical pads of tbuf (never overwritten afterwards)
  {
    int i = tid;                       // Cc*2*RAD = 420 < NT: single pass
    if (i < Cc * 2 * RAD) {
      int c = i / (2 * RAD), g = i % (2 * RAD);
      tbuf[c * TSTR + (g < RAD ? g : Hh + g)] = 0.f;
    }
  }
  __syncthreads();
  if (tid < Cc * Cc) {
    int a = tid / Cc, b = tid % Cc;
    float s = 0.f;
    #pragma unroll
    for (int kk = 0; kk < Cc; ++kk) s += cm_ld[a * Cc + kk] * wsum_ld[kk * Cc + b];
    M_ld[tid] = s;  // consumed in Phase C (covered by barriers below)
  }
  if (tid < Hh) {
    float s = 0.f;
    #pragma unroll
    for (int d = -RAD; d <= RAD; ++d) {
      int hp = tid + d;
      if (hp >= 0 && hp < Hh) s += w_ld[d < 0 ? -d : d];
    }
    ny_ld[tid] = s;  // truncated consistently with the blur
  }
  float nxv = 0.f;
  #pragma unroll
  for (int d = -RAD; d <= RAD; ++d) {
    int xp = x + d;
    if (xp >= 0 && xp < Ww) nxv += w_ld[d < 0 ? -d : d];
  }

  // ---- p0 = softmax(u): into qbuf, pack bf16 -> pa, post epoch 1 ----
  #pragma unroll
  for (int k = 0; k < 4; ++k) {
    int i = tid + NT * k;
    if (i < COLSZ) qbuf[i] = uval[k];
  }
  __syncthreads();
  softmax_rows(qbuf);
  __syncthreads();
  if (tid < NF4) {   // pack 4 fp32 -> 4 bf16 in one 8B coherent store
    float4 v = *(const float4*)(qbuf + 4 * tid);
    unsigned lo = (unsigned)f2bf(v.x) | ((unsigned)f2bf(v.y) << 16);
    unsigned hi = (unsigned)f2bf(v.z) | ((unsigned)f2bf(v.w) << 16);
    unsigned long long o = (unsigned long long)lo | ((unsigned long long)hi << 32);
    __hip_atomic_store(pa + (size_t)x * NF4 + tid, o,
                       __ATOMIC_RELAXED, __HIP_MEMORY_SCOPE_AGENT);
  }
  post_flag(flags, x, 1u);

  const unsigned long long* pin = pa;
  unsigned long long* pout = pb;

  for (int it = 0; it < 5; ++it) {
    const int last = (it == 4);

    // ---- wait for the 21 clamped neighbor columns to reach this epoch ----
    wait_neighbors(flags, x, (unsigned)(it + 1));

    // ---- Phase A: H-blur. Preload ALL 21 taps into registers first (one
    // IF-latency batch; R11's 56-VGPR build serialized ~4 batches), then
    // unpack+FMA. Static indexing after unroll -> registers, not scratch.
    const bool af = (tid < NF4);
    float4 acc = {0.f, 0.f, 0.f, 0.f};
    if (af) {
      unsigned long long pv[2 * RAD + 1];
      #pragma unroll
      for (int d = -RAD; d <= RAD; ++d) {
        int xs = x + d;
        int xc = xs < 0 ? 0 : (xs >= Ww ? Ww - 1 : xs);
        pv[d + RAD] = __hip_atomic_load(pin + (size_t)xc * NF4 + tid,
                                        __ATOMIC_RELAXED,
                                        __HIP_MEMORY_SCOPE_AGENT);
      }
      #pragma unroll
      for (int d = -RAD; d <= RAD; ++d) {
        int xs = x + d;
        float wv = (xs >= 0 && xs < Ww) ? w_ld[d < 0 ? -d : d] : 0.f;
        unsigned lo = (unsigned)pv[d + RAD];
        unsigned hi = (unsigned)(pv[d + RAD] >> 32);
        acc.x += wv * bf2f_lo(lo); acc.y += wv * bf2f_hi(lo);
        acc.z += wv * bf2f_lo(hi); acc.w += wv * bf2f_hi(hi);
      }
      // scatter into transposed padded tbuf [c][RAD+h]
      float a4[4] = {acc.x, acc.y, acc.z, acc.w};
      #pragma unroll
      for (int e = 0; e < 4; ++e) {
        int i = 4 * tid + e;
        tbuf[(i % Cc) * TSTR + RAD + (i / Cc)] = a4[e];
      }
    }
    __syncthreads();

    // ---- Phase B: V-blur (aligned float4 LDS reads) + normalize ----
    if (tid < NF4) {               // 504 = 21 c * 24 h-quads
      int c = tid / 24, q = tid % 24;
      int h0 = 4 * q;
      const float* base = tbuf + c * TSTR + h0;  // padded idx of h0-RAD
      float r[4] = {0.f, 0.f, 0.f, 0.f};
      #pragma unroll
      for (int jj = 0; jj < 6; ++jj) {      // offsets 0..23 cover d in [-10,13]
        float4 tv = *(const float4*)(base + 4 * jj);
        float tvv[4] = {tv.x, tv.y, tv.z, tv.w};
        #pragma unroll
        for (int kk = 0; kk < 4; ++kk) {
          #pragma unroll
          for (int o = 0; o < 4; ++o) {
            int d = 4 * jj + kk - RAD - o;  // compile-time after unroll
            int ad = d < 0 ? -d : d;
            if (ad <= RAD) r[o] += w_ld[ad] * tvv[kk];
          }
        }
      }
      #pragma unroll
      for (int o = 0; o < 4; ++o)
        sbuf[(h0 + o) * Cc + c] = r[o] / (nxv * ny_ld[h0 + o]);
    }
    __syncthreads();

    // ---- Phase C: q = u - M@s, then softmax->bf16 (or raw fp32 if last) ----
    #pragma unroll
    for (int k = 0; k < 4; ++k) {
      int i = tid + NT * k;
      if (i < COLSZ) {
        int h = i / Cc, c = i % Cc;
        float a = 0.f;
        #pragma unroll
        for (int b = 0; b < Cc; ++b) a += M_ld[c * Cc + b] * sbuf[h * Cc + b];
        qbuf[i] = uval[k] - a;
      }
    }
    __syncthreads();
    if (last) {                    // block-uniform branch
      if (tid < NF4)
        *(float4*)(qout + (size_t)x * COLSZ + 4 * tid) = *(const float4*)(qbuf + 4 * tid);
    } else {
      softmax_rows(qbuf);
      __syncthreads();
      if (tid < NF4) {
        float4 v = *(const float4*)(qbuf + 4 * tid);
        unsigned lo = (unsigned)f2bf(v.x) | ((unsigned)f2bf(v.y) << 16);
        unsigned hi = (unsigned)f2bf(v.z) | ((unsigned)f2bf(v.w) << 16);
        unsigned long long o = (unsigned long long)lo | ((unsigned long long)hi << 32);
        __hip_atomic_store(pout + (size_t)x * NF4 + tid, o,
                           __ATOMIC_RELAXED, __HIP_MEMORY_SCOPE_AGENT);
      }
      post_flag(flags, x, (unsigned)(it + 2));
      const unsigned long long* t = pin; pin = pout;
      pout = (unsigned long long*)t;
    }
  }
}

// ---------------------------------------------------------------------------
extern "C" void kernel_launch(void* const* d_in, const int* in_sizes, int n_in,
                              void* d_out, int out_size, void* d_ws, size_t ws_size,
                              hipStream_t stream) {
  const float* u      = (const float*)d_in[0];  // (1,H,W,C)
  // d_in[1] = rgb: DEAD (replicated source bug uses spatial_out twice)
  const float* Ws     = (const float*)d_in[2];
  const float* Wb     = (const float*)d_in[3];
  const float* compat = (const float*)d_in[4];
  float* out = (float*)d_out;

  unsigned long long* pa = (unsigned long long*)d_ws;  // bf16x4 per 8B
  unsigned long long* pb = pa + (size_t)Ww * NF4;
  unsigned int* flags = (unsigned int*)(pb + (size_t)Ww * NF4);

  // Zero flag state EVERY launch (graph-capturable stream op).
  hipMemsetAsync(flags, 0, Ww * FSTR * sizeof(unsigned), stream);

  crf_fused_k<<<dim3(Ww), dim3(NT), 0, stream>>>(u, Ws, Wb, compat,
                                                 pa, pb, flags, out);
}